// Round 1
// baseline (930.140 us; speedup 1.0000x reference)
//
#include <hip/hip_runtime.h>

#define NC 100000
#define NF 400000
#define NE 1600000
#define C  64

// One thread per (edge, channel): coalesced 64-lane row access on both the
// gather (x[src]) and the scatter (agg[dst]); src/dst/w loads are wave-uniform
// (same address across the 64 lanes of an edge -> broadcast).
__global__ __launch_bounds__(256) void k_scatter_coarse(
    const float* __restrict__ x, const int* __restrict__ src,
    const int* __restrict__ dst, const float* __restrict__ w,
    float* __restrict__ agg)
{
    int idx = blockIdx.x * 256 + threadIdx.x;   // up to NE*64 = 102.4M < 2^31
    int e = idx >> 6;
    if (e >= NE) return;
    int c = idx & 63;
    float v = w[e] * x[src[e] * C + c];
    atomicAdd(&agg[dst[e] * C + c], v);
}

// h = agg @ W + b. W staged in LDS (16 KiB). 4 rows/block, one lane per
// output column. Ws[k*64+c] across lanes: bank = c%32 -> 2-way, free.
// ar[k] is wave-uniform -> broadcast.
__global__ __launch_bounds__(256) void k_gemm(
    const float* __restrict__ agg, const float* __restrict__ W,
    const float* __restrict__ b, float* __restrict__ h)
{
    __shared__ float Ws[64 * 64];
    int tid = threadIdx.x;
    #pragma unroll
    for (int i = 0; i < 16; ++i) Ws[i * 256 + tid] = W[i * 256 + tid];
    __syncthreads();
    int row = blockIdx.x * 4 + (tid >> 6);
    if (row >= NC) return;
    int c = tid & 63;
    const float* __restrict__ ar = agg + row * C;
    float acc = b[c];
    #pragma unroll
    for (int k = 0; k < 64; ++k) acc = fmaf(ar[k], Ws[k * 64 + c], acc);
    h[row * C + c] = acc;
}

__global__ __launch_bounds__(256) void k_scatter_fine(
    const float* __restrict__ h, const int* __restrict__ psrc,
    const int* __restrict__ pdst, const float* __restrict__ pw,
    float* __restrict__ out)
{
    int idx = blockIdx.x * 256 + threadIdx.x;
    int e = idx >> 6;
    if (e >= NE) return;
    int c = idx & 63;
    float v = pw[e] * h[psrc[e] * C + c];
    atomicAdd(&out[pdst[e] * C + c], v);
}

// out[fwd[i]] = h[i]  (overwrite; fwd rows are unique)
__global__ __launch_bounds__(256) void k_inject(
    const float* __restrict__ h, const int* __restrict__ fwd,
    float* __restrict__ out)
{
    int idx = blockIdx.x * 256 + threadIdx.x;
    int i = idx >> 6;
    if (i >= NC) return;
    int c = idx & 63;
    out[fwd[i] * C + c] = h[i * C + c];
}

extern "C" void kernel_launch(void* const* d_in, const int* in_sizes, int n_in,
                              void* d_out, int out_size, void* d_ws, size_t ws_size,
                              hipStream_t stream) {
    const float* x    = (const float*)d_in[0];
    const float* W    = (const float*)d_in[1];
    const float* b    = (const float*)d_in[2];
    const int*   ei   = (const int*)d_in[3];   // [2,E] flat: src = ei, dst = ei+E
    const float* ea   = (const float*)d_in[4];
    const int*   psrc = (const int*)d_in[5];
    const int*   pdst = (const int*)d_in[6];
    const float* pw   = (const float*)d_in[7];
    const int*   fwd  = (const int*)d_in[8];
    float* out = (float*)d_out;

    float* agg = (float*)d_ws;                  // NC*C fp32 = 25.6 MB
    float* h   = agg + (size_t)NC * C;          // NC*C fp32 = 25.6 MB

    hipMemsetAsync(agg, 0, (size_t)NC * C * sizeof(float), stream);
    hipMemsetAsync(out, 0, (size_t)NF * C * sizeof(float), stream);

    {
        int total = NE * 64;
        k_scatter_coarse<<<(total + 255) / 256, 256, 0, stream>>>(x, ei, ei + NE, ea, agg);
    }
    k_gemm<<<(NC + 3) / 4, 256, 0, stream>>>(agg, W, b, h);
    {
        int total = NE * 64;
        k_scatter_fine<<<(total + 255) / 256, 256, 0, stream>>>(h, psrc, pdst, pw, out);
    }
    {
        int total = NC * 64;
        k_inject<<<(total + 255) / 256, 256, 0, stream>>>(h, fwd, out);
    }
}